// Round 5
// baseline (262.716 us; speedup 1.0000x reference)
//
#include <hip/hip_runtime.h>
#include <math.h>

#define BATCH 2
#define SEQ   2048
#define CDIM  1024
#define NHEAD 16
#define HDIM  64
#define TOKS  (BATCH * SEQ)   // 4096

typedef __bf16 bf16x8 __attribute__((ext_vector_type(8)));
typedef __bf16 bf16x2 __attribute__((ext_vector_type(2)));
typedef float  f32x4  __attribute__((ext_vector_type(4)));

#define MFMA16(a, b, c) __builtin_amdgcn_mfma_f32_16x16x32_bf16(a, b, c, 0, 0, 0)

// 0.125 * log2(e): folded into Q projection so p = exp2(s) == softmax-exact
#define QSCALE 0.1803368801111204f

__device__ __forceinline__ void gload_lds16(const __bf16* g, __bf16* l) {
    __builtin_amdgcn_global_load_lds(
        (const __attribute__((address_space(1))) unsigned int*)g,
        (__attribute__((address_space(3))) unsigned int*)l, 16, 0, 0);
}

// ---------------------------------------------------------------------------
// Prep: blocks [0,6144): fp32->bf16 convert of q,k,v (2048 blocks each).
//       blocks [6144,7168): W (KxN fp32) -> Wt (NxK bf16) transpose, 4 mats.
// ---------------------------------------------------------------------------
__global__ __launch_bounds__(256) void prep_kernel(
    const float* __restrict__ q, const float* __restrict__ k, const float* __restrict__ v,
    __bf16* __restrict__ qo, __bf16* __restrict__ ko, __bf16* __restrict__ vo,
    const float* __restrict__ W0, const float* __restrict__ W1,
    const float* __restrict__ W2, const float* __restrict__ W3,
    __bf16* __restrict__ T0, __bf16* __restrict__ T1,
    __bf16* __restrict__ T2, __bf16* __restrict__ T3)
{
    __shared__ __bf16 Ts[64][72];
    const int bx = blockIdx.x;
    const int tid = threadIdx.x;

    if (bx < 6144) {
        const int t = bx >> 11;
        const size_t i = ((size_t)(bx & 2047) * 256 + tid) * 8;
        const float* s = t == 0 ? q : (t == 1 ? k : v);
        __bf16* d = t == 0 ? qo : (t == 1 ? ko : vo);
        const float4 x = *(const float4*)&s[i];
        const float4 y = *(const float4*)&s[i + 4];
        bf16x8 o;
        o[0] = (__bf16)x.x; o[1] = (__bf16)x.y; o[2] = (__bf16)x.z; o[3] = (__bf16)x.w;
        o[4] = (__bf16)y.x; o[5] = (__bf16)y.y; o[6] = (__bf16)y.z; o[7] = (__bf16)y.w;
        *(bf16x8*)&d[i] = o;
        return;
    }

    const int t  = bx - 6144;
    const int z  = t >> 8;
    const int ry = (t & 255) >> 4;
    const int rx = t & 15;
    const float* W = z == 0 ? W0 : z == 1 ? W1 : z == 2 ? W2 : W3;
    __bf16* T = z == 0 ? T0 : z == 1 ? T1 : z == 2 ? T2 : T3;
    const int rb = ry * 64, cb = rx * 64;
    const int r = tid >> 4;
    const int c4 = (tid & 15) * 4;
#pragma unroll
    for (int p = 0; p < 4; p++) {
        const int rr = p * 16 + r;
        const float4 w4 = *(const float4*)&W[(size_t)(rb + rr) * CDIM + cb + c4];
        Ts[c4 + 0][rr] = (__bf16)w4.x;
        Ts[c4 + 1][rr] = (__bf16)w4.y;
        Ts[c4 + 2][rr] = (__bf16)w4.z;
        Ts[c4 + 3][rr] = (__bf16)w4.w;
    }
    __syncthreads();
    const int n = tid >> 2;
    const int k16 = (tid & 3) * 16;
    *(bf16x8*)&T[(size_t)(cb + n) * CDIM + rb + k16]     = *(const bf16x8*)&Ts[n][k16];
    *(bf16x8*)&T[(size_t)(cb + n) * CDIM + rb + k16 + 8] = *(const bf16x8*)&Ts[n][k16 + 8];
}

// ---------------------------------------------------------------------------
// Fused QKV projection GEMM (m97 structure), one dispatch, z selects:
//   z=0: Qh = (q@Wq + bq)*QSCALE  -> (B,H,L,D) bf16
//   z=1: Kh = (k@Wk + bk)         -> (B,H,L,D) bf16
//   z=2: Vht = (Wv^T @ v^T + bv)  -> [chan][tok'] bf16, tok' key-pair-permuted
//        within each 32-group: pos(n) = 2*(n&15) + (n>>4)  (for attn P pairing)
// ---------------------------------------------------------------------------
__global__ __launch_bounds__(256) void qkv_gemm_kernel(
    const __bf16* __restrict__ qb, const __bf16* __restrict__ kb,
    const __bf16* __restrict__ vb,
    const __bf16* __restrict__ Wqt, const __bf16* __restrict__ Wkt,
    const __bf16* __restrict__ Wvt,
    const float* __restrict__ bq, const float* __restrict__ bk,
    const float* __restrict__ bv,
    __bf16* __restrict__ Qh, __bf16* __restrict__ Kh, __bf16* __restrict__ Vht)
{
    __shared__ __bf16 As[128 * 32];
    __shared__ __bf16 Bs[128 * 32];

    const int z = blockIdx.z;
    const __bf16* A    = z == 0 ? qb : z == 1 ? kb : Wvt;
    const __bf16* Bt   = z == 0 ? Wqt : z == 1 ? Wkt : vb;
    const float*  bias = z == 0 ? bq : z == 1 ? bk : bv;

    const int tid  = threadIdx.x;
    const int w    = tid >> 6;
    const int lane = tid & 63;
    const int quad = lane >> 4;
    const int c    = lane & 15;
    const int wm   = w >> 1;
    const int wn   = w & 1;
    const int rowBase = (z == 2 ? blockIdx.x : blockIdx.y) * 128;
    const int colBase = (z == 2 ? blockIdx.y : blockIdx.x) * 128;

    const int sr = lane >> 2;
    const int sk = (lane & 3) * 8;

    f32x4 acc[4][4];
#pragma unroll
    for (int i = 0; i < 4; i++)
#pragma unroll
        for (int j = 0; j < 4; j++) acc[i][j] = (f32x4){0, 0, 0, 0};

    for (int k0 = 0; k0 < CDIM; k0 += 32) {
#pragma unroll
        for (int j = 0; j < 2; j++) {
            const int r0 = (w * 2 + j) * 16;
            gload_lds16(A  + (size_t)(rowBase + r0 + sr) * CDIM + k0 + sk, &As[r0 * 32]);
            gload_lds16(Bt + (size_t)(colBase + r0 + sr) * CDIM + k0 + sk, &Bs[r0 * 32]);
        }
        __syncthreads();

        bf16x8 af[4], bf[4];
#pragma unroll
        for (int i = 0; i < 4; i++) {
            af[i] = *(const bf16x8*)&As[(wm * 64 + i * 16 + c) * 32 + quad * 8];
            bf[i] = *(const bf16x8*)&Bs[(wn * 64 + i * 16 + c) * 32 + quad * 8];
        }
#pragma unroll
        for (int mi = 0; mi < 4; mi++)
#pragma unroll
            for (int ni = 0; ni < 4; ni++)
                acc[mi][ni] = MFMA16(af[mi], bf[ni], acc[mi][ni]);
        __syncthreads();
    }

#pragma unroll
    for (int mi = 0; mi < 4; mi++) {
#pragma unroll
        for (int ni = 0; ni < 4; ni++) {
            const int col = colBase + wn * 64 + ni * 16 + c;
#pragma unroll
            for (int r = 0; r < 4; r++) {
                const int row = rowBase + wm * 64 + mi * 16 + quad * 4 + r;
                const float val = acc[mi][ni][r];
                if (z == 2) {
                    // permuted-tok V write: pos within 32-group = 2*(n&15)+(n>>4)
                    const int col2 = (col & ~31) | (((col & 15) << 1) | ((col >> 4) & 1));
                    Vht[(size_t)row * TOKS + col2] = (__bf16)(val + bias[row]);
                } else {
                    const int b = row >> 11, l = row & 2047;
                    const int h = col >> 6,  d = col & 63;
                    const float s = (z == 0) ? QSCALE : 1.0f;
                    __bf16* outp = (z == 0) ? Qh : Kh;
                    outp[((((size_t)b * NHEAD + h) * SEQ) + l) * HDIM + d] =
                        (__bf16)((val + bias[col]) * s);
                }
            }
        }
    }
}

// ---------------------------------------------------------------------------
// Final projection GEMM: out(fp32) = Yb(bf16) @ Wot^T + bo.
// 128x64 tile -> grid (16,32) = 512 blocks (2 blocks/CU for overlap).
// ---------------------------------------------------------------------------
__global__ __launch_bounds__(256) void out_gemm_kernel(
    const __bf16* __restrict__ A, const __bf16* __restrict__ Bt,
    const float* __restrict__ bias, float* __restrict__ out)
{
    __shared__ __bf16 As[128 * 32];
    __shared__ __bf16 Bs[64 * 32];

    const int tid  = threadIdx.x;
    const int w    = tid >> 6;
    const int lane = tid & 63;
    const int quad = lane >> 4;
    const int c    = lane & 15;
    const int wm   = w >> 1;                 // 0..1 : 64-row half
    const int wn   = w & 1;                  // 0..1 : 32-col half
    const int rowBase = blockIdx.y * 128;
    const int colBase = blockIdx.x * 64;
    const int sr = lane >> 2;
    const int sk = (lane & 3) * 8;

    f32x4 acc[4][2];
#pragma unroll
    for (int i = 0; i < 4; i++)
#pragma unroll
        for (int j = 0; j < 2; j++) acc[i][j] = (f32x4){0, 0, 0, 0};

    for (int k0 = 0; k0 < CDIM; k0 += 32) {
#pragma unroll
        for (int j = 0; j < 2; j++) {
            const int r0 = (w * 2 + j) * 16;
            gload_lds16(A + (size_t)(rowBase + r0 + sr) * CDIM + k0 + sk, &As[r0 * 32]);
        }
        gload_lds16(Bt + (size_t)(colBase + w * 16 + sr) * CDIM + k0 + sk, &Bs[w * 16 * 32]);
        __syncthreads();

        bf16x8 af[4], bf[2];
#pragma unroll
        for (int i = 0; i < 4; i++)
            af[i] = *(const bf16x8*)&As[(wm * 64 + i * 16 + c) * 32 + quad * 8];
#pragma unroll
        for (int i = 0; i < 2; i++)
            bf[i] = *(const bf16x8*)&Bs[(wn * 32 + i * 16 + c) * 32 + quad * 8];
#pragma unroll
        for (int mi = 0; mi < 4; mi++)
#pragma unroll
            for (int ni = 0; ni < 2; ni++)
                acc[mi][ni] = MFMA16(af[mi], bf[ni], acc[mi][ni]);
        __syncthreads();
    }

#pragma unroll
    for (int mi = 0; mi < 4; mi++) {
#pragma unroll
        for (int ni = 0; ni < 2; ni++) {
            const int col = colBase + wn * 32 + ni * 16 + c;
#pragma unroll
            for (int r = 0; r < 4; r++) {
                const int row = rowBase + wm * 64 + mi * 16 + quad * 4 + r;
                out[(size_t)row * CDIM + col] = acc[mi][ni][r] + bias[col];
            }
        }
    }
}

// ---------------------------------------------------------------------------
// Attention v3: one wave per 64 q-rows; NO K/V LDS staging (direct global
// b128 fragment loads, L2-resident), no barriers; double-buffered prefetch.
// LDS only for the P transpose: paired-column layout (cols n, n+16 in one
// dword), 36-dword rows -> conflict-free b32 stores and b128 reads.
// Q pre-scaled by 0.125*log2e so p = exp2(s); no running max (|s| small).
// V is stored tok-permuted by the projection so PV fragments read linearly.
// ---------------------------------------------------------------------------
struct AttnRegs {
    bf16x8 k[4];
    bf16x8 v[4];
};

__global__ __launch_bounds__(64) void attn_v3_kernel(
    const __bf16* __restrict__ Qh, const __bf16* __restrict__ Kh,
    const __bf16* __restrict__ Vht, __bf16* __restrict__ Y)
{
    __shared__ unsigned int Pf[4][16][36];   // [g][qrow][col-pair] packed bf16x2

    const int lane = threadIdx.x;            // 0..63
    const int quad = lane >> 4;
    const int c    = lane & 15;
    const int qt   = blockIdx.x;             // 0..31 (64-q tile)
    const int bh   = blockIdx.y;             // 0..31
    const int b    = bh >> 4;
    const int h    = bh & 15;
    const int qbase = qt * 64;

    const __bf16* Qg = Qh + (size_t)bh * SEQ * HDIM;
    const __bf16* Kg = Kh + (size_t)bh * SEQ * HDIM;
    const __bf16* Vg = Vht + (size_t)(h * HDIM) * TOKS + (size_t)b * SEQ;

    bf16x8 qf[4][2];
#pragma unroll
    for (int g = 0; g < 4; g++) {
        qf[g][0] = *(const bf16x8*)&Qg[(size_t)(qbase + g * 16 + c) * HDIM + quad * 8];
        qf[g][1] = *(const bf16x8*)&Qg[(size_t)(qbase + g * 16 + c) * HDIM + 32 + quad * 8];
    }

    bf16x8 ones;
#pragma unroll
    for (int j = 0; j < 8; j++) ones[j] = (__bf16)1.0f;

    f32x4 O[4][4];
    f32x4 L[4];
#pragma unroll
    for (int g = 0; g < 4; g++) {
        L[g] = (f32x4){0, 0, 0, 0};
#pragma unroll
        for (int i = 0; i < 4; i++) O[g][i] = (f32x4){0, 0, 0, 0};
    }

    AttnRegs ra, rb;

    // fragment load helper offsets
    const size_t kOff0 = (size_t)c * HDIM + quad * 8;
    const size_t kOff1 = kOff0 + 32;
    const size_t kOff2 = (size_t)(16 + c) * HDIM + quad * 8;
    const size_t kOff3 = kOff2 + 32;

    auto load_tile = [&](AttnRegs& r, int t) {
        r.k[0] = *(const bf16x8*)&Kg[(size_t)t * HDIM + kOff0];
        r.k[1] = *(const bf16x8*)&Kg[(size_t)t * HDIM + kOff1];
        r.k[2] = *(const bf16x8*)&Kg[(size_t)t * HDIM + kOff2];
        r.k[3] = *(const bf16x8*)&Kg[(size_t)t * HDIM + kOff3];
#pragma unroll
        for (int i = 0; i < 4; i++)
            r.v[i] = *(const bf16x8*)&Vg[(size_t)(c + 16 * i) * TOKS + t + quad * 8];
    };

    auto step = [&](const AttnRegs& cur) {
        // S = Q K^T : two 16-key halves per g
#pragma unroll
        for (int g = 0; g < 4; g++) {
            f32x4 s0 = {0, 0, 0, 0}, s1 = {0, 0, 0, 0};
            s0 = MFMA16(qf[g][0], cur.k[0], s0);
            s0 = MFMA16(qf[g][1], cur.k[1], s0);
            s1 = MFMA16(qf[g][0], cur.k[2], s1);
            s1 = MFMA16(qf[g][1], cur.k[3], s1);
#pragma unroll
            for (int r = 0; r < 4; r++) {
                union { bf16x2 v; unsigned int u; } pk;
                pk.v[0] = (__bf16)__builtin_amdgcn_exp2f(s0[r]);
                pk.v[1] = (__bf16)__builtin_amdgcn_exp2f(s1[r]);
                Pf[g][quad * 4 + r][c] = pk.u;
            }
        }
        // PV + row-sum (ones MFMA); P read back in A-layout (paired cols)
#pragma unroll
        for (int g = 0; g < 4; g++) {
            const bf16x8 pf = *(const bf16x8*)&Pf[g][c][quad * 4];
            L[g]    = MFMA16(pf, ones, L[g]);
            O[g][0] = MFMA16(pf, cur.v[0], O[g][0]);
            O[g][1] = MFMA16(pf, cur.v[1], O[g][1]);
            O[g][2] = MFMA16(pf, cur.v[2], O[g][2]);
            O[g][3] = MFMA16(pf, cur.v[3], O[g][3]);
        }
    };

    load_tile(ra, 0);
    for (int t0 = 0; t0 < SEQ; t0 += 64) {
        load_tile(rb, (t0 + 32) & (SEQ - 1));
        step(ra);
        load_tile(ra, (t0 + 64) & (SEQ - 1));
        step(rb);
    }

    __bf16* Yb = Y + (size_t)b * SEQ * CDIM;
#pragma unroll
    for (int g = 0; g < 4; g++) {
#pragma unroll
        for (int r = 0; r < 4; r++) {
            const float inv = 1.0f / L[g][r];
            const int l = qbase + g * 16 + quad * 4 + r;
            __bf16* yp = Yb + (size_t)l * CDIM + h * HDIM + c;
            yp[0]  = (__bf16)(O[g][0][r] * inv);
            yp[16] = (__bf16)(O[g][1][r] * inv);
            yp[32] = (__bf16)(O[g][2][r] * inv);
            yp[48] = (__bf16)(O[g][3][r] * inv);
        }
    }
}

// ---------------------------------------------------------------------------

extern "C" void kernel_launch(void* const* d_in, const int* in_sizes, int n_in,
                              void* d_out, int out_size, void* d_ws, size_t ws_size,
                              hipStream_t stream)
{
    const float* q  = (const float*)d_in[0];
    const float* k  = (const float*)d_in[1];
    const float* v  = (const float*)d_in[2];
    const float* Wq = (const float*)d_in[3];
    const float* bq = (const float*)d_in[4];
    const float* Wk = (const float*)d_in[5];
    const float* bk = (const float*)d_in[6];
    const float* Wv = (const float*)d_in[7];
    const float* bv = (const float*)d_in[8];
    const float* Wo = (const float*)d_in[9];
    const float* bo = (const float*)d_in[10];
    float* out = (float*)d_out;

    const size_t MAT = (size_t)TOKS * CDIM;
    const size_t WN  = (size_t)CDIM * CDIM;

    __bf16* p   = (__bf16*)d_ws;
    __bf16* qb  = p; p += MAT;
    __bf16* kb  = p; p += MAT;
    __bf16* vb  = p; p += MAT;
    __bf16* Wqt = p; p += WN;
    __bf16* Wkt = p; p += WN;
    __bf16* Wvt = p; p += WN;
    __bf16* Wot = p; p += WN;
    __bf16* Qh  = p; p += MAT;   // (B,H,L,D), scaled by QSCALE
    __bf16* Kh  = p; p += MAT;   // (B,H,L,D)
    __bf16* Vht = p; p += MAT;   // [chan][tok'], pair-permuted toks
    __bf16* Yb  = qb;            // alias: qb dead after QKV GEMM

    prep_kernel<<<dim3(7168), dim3(256), 0, stream>>>(
        q, k, v, qb, kb, vb, Wq, Wk, Wv, Wo, Wqt, Wkt, Wvt, Wot);

    qkv_gemm_kernel<<<dim3(8, 32, 3), dim3(256), 0, stream>>>(
        qb, kb, vb, Wqt, Wkt, Wvt, bq, bk, bv, Qh, Kh, Vht);

    attn_v3_kernel<<<dim3(32, 32), dim3(64), 0, stream>>>(Qh, Kh, Vht, Yb);

    out_gemm_kernel<<<dim3(16, 32), dim3(256), 0, stream>>>(Yb, Wot, bo, out);
}

// Round 6
// 240.921 us; speedup vs baseline: 1.0905x; 1.0905x over previous
//
#include <hip/hip_runtime.h>
#include <math.h>

#define BATCH 2
#define SEQ   2048
#define CDIM  1024
#define NHEAD 16
#define HDIM  64
#define TOKS  (BATCH * SEQ)   // 4096

typedef __bf16 bf16x8 __attribute__((ext_vector_type(8)));
typedef __bf16 bf16x2 __attribute__((ext_vector_type(2)));
typedef float  f32x4  __attribute__((ext_vector_type(4)));

#define MFMA16(a, b, c) __builtin_amdgcn_mfma_f32_16x16x32_bf16(a, b, c, 0, 0, 0)

// 0.125 * log2(e): folded into Q projection so p = exp2(s) == softmax-exact
#define QSCALE 0.1803368801111204f

__device__ __forceinline__ void gload_lds16(const __bf16* g, __bf16* l) {
    __builtin_amdgcn_global_load_lds(
        (const __attribute__((address_space(1))) unsigned int*)g,
        (__attribute__((address_space(3))) unsigned int*)l, 16, 0, 0);
}

// ---------------------------------------------------------------------------
// Prep: blocks [0,6144): fp32->bf16 convert of q,k,v (2048 blocks each).
//       blocks [6144,7168): W (KxN fp32) -> Wt (NxK bf16) transpose, 4 mats.
// ---------------------------------------------------------------------------
__global__ __launch_bounds__(256) void prep_kernel(
    const float* __restrict__ q, const float* __restrict__ k, const float* __restrict__ v,
    __bf16* __restrict__ qo, __bf16* __restrict__ ko, __bf16* __restrict__ vo,
    const float* __restrict__ W0, const float* __restrict__ W1,
    const float* __restrict__ W2, const float* __restrict__ W3,
    __bf16* __restrict__ T0, __bf16* __restrict__ T1,
    __bf16* __restrict__ T2, __bf16* __restrict__ T3)
{
    __shared__ __bf16 Ts[64][72];
    const int bx = blockIdx.x;
    const int tid = threadIdx.x;

    if (bx < 6144) {
        const int t = bx >> 11;
        const size_t i = ((size_t)(bx & 2047) * 256 + tid) * 8;
        const float* s = t == 0 ? q : (t == 1 ? k : v);
        __bf16* d = t == 0 ? qo : (t == 1 ? ko : vo);
        const float4 x = *(const float4*)&s[i];
        const float4 y = *(const float4*)&s[i + 4];
        bf16x8 o;
        o[0] = (__bf16)x.x; o[1] = (__bf16)x.y; o[2] = (__bf16)x.z; o[3] = (__bf16)x.w;
        o[4] = (__bf16)y.x; o[5] = (__bf16)y.y; o[6] = (__bf16)y.z; o[7] = (__bf16)y.w;
        *(bf16x8*)&d[i] = o;
        return;
    }

    const int t  = bx - 6144;
    const int z  = t >> 8;
    const int ry = (t & 255) >> 4;
    const int rx = t & 15;
    const float* W = z == 0 ? W0 : z == 1 ? W1 : z == 2 ? W2 : W3;
    __bf16* T = z == 0 ? T0 : z == 1 ? T1 : z == 2 ? T2 : T3;
    const int rb = ry * 64, cb = rx * 64;
    const int r = tid >> 4;
    const int c4 = (tid & 15) * 4;
#pragma unroll
    for (int p = 0; p < 4; p++) {
        const int rr = p * 16 + r;
        const float4 w4 = *(const float4*)&W[(size_t)(rb + rr) * CDIM + cb + c4];
        Ts[c4 + 0][rr] = (__bf16)w4.x;
        Ts[c4 + 1][rr] = (__bf16)w4.y;
        Ts[c4 + 2][rr] = (__bf16)w4.z;
        Ts[c4 + 3][rr] = (__bf16)w4.w;
    }
    __syncthreads();
    const int n = tid >> 2;
    const int k16 = (tid & 3) * 16;
    *(bf16x8*)&T[(size_t)(cb + n) * CDIM + rb + k16]     = *(const bf16x8*)&Ts[n][k16];
    *(bf16x8*)&T[(size_t)(cb + n) * CDIM + rb + k16 + 8] = *(const bf16x8*)&Ts[n][k16 + 8];
}

// ---------------------------------------------------------------------------
// Fused QKV projection GEMM (m97 structure), one dispatch, z selects:
//   z=0: Qh = (q@Wq + bq)*QSCALE  -> (B,H,L,D) bf16
//   z=1: Kh = (k@Wk + bk)         -> (B,H,L,D) bf16
//   z=2: Vht = (Wv^T @ v^T + bv)  -> [chan][tok'] bf16, tok' key-pair-permuted
//        within each 32-group: pos(n) = 2*(n&15) + (n>>4)  (for attn P pairing)
// ---------------------------------------------------------------------------
__global__ __launch_bounds__(256) void qkv_gemm_kernel(
    const __bf16* __restrict__ qb, const __bf16* __restrict__ kb,
    const __bf16* __restrict__ vb,
    const __bf16* __restrict__ Wqt, const __bf16* __restrict__ Wkt,
    const __bf16* __restrict__ Wvt,
    const float* __restrict__ bq, const float* __restrict__ bk,
    const float* __restrict__ bv,
    __bf16* __restrict__ Qh, __bf16* __restrict__ Kh, __bf16* __restrict__ Vht)
{
    __shared__ __bf16 As[128 * 32];
    __shared__ __bf16 Bs[128 * 32];

    const int z = blockIdx.z;
    const __bf16* A    = z == 0 ? qb : z == 1 ? kb : Wvt;
    const __bf16* Bt   = z == 0 ? Wqt : z == 1 ? Wkt : vb;
    const float*  bias = z == 0 ? bq : z == 1 ? bk : bv;

    const int tid  = threadIdx.x;
    const int w    = tid >> 6;
    const int lane = tid & 63;
    const int quad = lane >> 4;
    const int c    = lane & 15;
    const int wm   = w >> 1;
    const int wn   = w & 1;
    const int rowBase = (z == 2 ? blockIdx.x : blockIdx.y) * 128;
    const int colBase = (z == 2 ? blockIdx.y : blockIdx.x) * 128;

    const int sr = lane >> 2;
    const int sk = (lane & 3) * 8;

    f32x4 acc[4][4];
#pragma unroll
    for (int i = 0; i < 4; i++)
#pragma unroll
        for (int j = 0; j < 4; j++) acc[i][j] = (f32x4){0, 0, 0, 0};

    for (int k0 = 0; k0 < CDIM; k0 += 32) {
#pragma unroll
        for (int j = 0; j < 2; j++) {
            const int r0 = (w * 2 + j) * 16;
            gload_lds16(A  + (size_t)(rowBase + r0 + sr) * CDIM + k0 + sk, &As[r0 * 32]);
            gload_lds16(Bt + (size_t)(colBase + r0 + sr) * CDIM + k0 + sk, &Bs[r0 * 32]);
        }
        __syncthreads();

        bf16x8 af[4], bf[4];
#pragma unroll
        for (int i = 0; i < 4; i++) {
            af[i] = *(const bf16x8*)&As[(wm * 64 + i * 16 + c) * 32 + quad * 8];
            bf[i] = *(const bf16x8*)&Bs[(wn * 64 + i * 16 + c) * 32 + quad * 8];
        }
#pragma unroll
        for (int mi = 0; mi < 4; mi++)
#pragma unroll
            for (int ni = 0; ni < 4; ni++)
                acc[mi][ni] = MFMA16(af[mi], bf[ni], acc[mi][ni]);
        __syncthreads();
    }

#pragma unroll
    for (int mi = 0; mi < 4; mi++) {
#pragma unroll
        for (int ni = 0; ni < 4; ni++) {
            const int col = colBase + wn * 64 + ni * 16 + c;
#pragma unroll
            for (int r = 0; r < 4; r++) {
                const int row = rowBase + wm * 64 + mi * 16 + quad * 4 + r;
                const float val = acc[mi][ni][r];
                if (z == 2) {
                    // permuted-tok V write: pos within 32-group = 2*(n&15)+(n>>4)
                    const int col2 = (col & ~31) | (((col & 15) << 1) | ((col >> 4) & 1));
                    Vht[(size_t)row * TOKS + col2] = (__bf16)(val + bias[row]);
                } else {
                    const int b = row >> 11, l = row & 2047;
                    const int h = col >> 6,  d = col & 63;
                    const float s = (z == 0) ? QSCALE : 1.0f;
                    __bf16* outp = (z == 0) ? Qh : Kh;
                    outp[((((size_t)b * NHEAD + h) * SEQ) + l) * HDIM + d] =
                        (__bf16)((val + bias[col]) * s);
                }
            }
        }
    }
}

// ---------------------------------------------------------------------------
// Final projection GEMM: out(fp32) = Yb(bf16) @ Wot^T + bo.
// 128x64 tile -> grid (16,32) = 512 blocks (2 blocks/CU for overlap).
// ---------------------------------------------------------------------------
__global__ __launch_bounds__(256) void out_gemm_kernel(
    const __bf16* __restrict__ A, const __bf16* __restrict__ Bt,
    const float* __restrict__ bias, float* __restrict__ out)
{
    __shared__ __bf16 As[128 * 32];
    __shared__ __bf16 Bs[64 * 32];

    const int tid  = threadIdx.x;
    const int w    = tid >> 6;
    const int lane = tid & 63;
    const int quad = lane >> 4;
    const int c    = lane & 15;
    const int wm   = w >> 1;
    const int wn   = w & 1;
    const int rowBase = blockIdx.y * 128;
    const int colBase = blockIdx.x * 64;
    const int sr = lane >> 2;
    const int sk = (lane & 3) * 8;

    f32x4 acc[4][2];
#pragma unroll
    for (int i = 0; i < 4; i++)
#pragma unroll
        for (int j = 0; j < 2; j++) acc[i][j] = (f32x4){0, 0, 0, 0};

    for (int k0 = 0; k0 < CDIM; k0 += 32) {
#pragma unroll
        for (int j = 0; j < 2; j++) {
            const int r0 = (w * 2 + j) * 16;
            gload_lds16(A + (size_t)(rowBase + r0 + sr) * CDIM + k0 + sk, &As[r0 * 32]);
        }
        gload_lds16(Bt + (size_t)(colBase + w * 16 + sr) * CDIM + k0 + sk, &Bs[w * 16 * 32]);
        __syncthreads();

        bf16x8 af[4], bf[2];
#pragma unroll
        for (int i = 0; i < 4; i++)
            af[i] = *(const bf16x8*)&As[(wm * 64 + i * 16 + c) * 32 + quad * 8];
#pragma unroll
        for (int i = 0; i < 2; i++)
            bf[i] = *(const bf16x8*)&Bs[(wn * 32 + i * 16 + c) * 32 + quad * 8];
#pragma unroll
        for (int mi = 0; mi < 4; mi++)
#pragma unroll
            for (int ni = 0; ni < 2; ni++)
                acc[mi][ni] = MFMA16(af[mi], bf[ni], acc[mi][ni]);
        __syncthreads();
    }

#pragma unroll
    for (int mi = 0; mi < 4; mi++) {
#pragma unroll
        for (int ni = 0; ni < 2; ni++) {
            const int col = colBase + wn * 32 + ni * 16 + c;
#pragma unroll
            for (int r = 0; r < 4; r++) {
                const int row = rowBase + wm * 64 + mi * 16 + quad * 4 + r;
                out[(size_t)row * CDIM + col] = acc[mi][ni][r] + bias[col];
            }
        }
    }
}

// ---------------------------------------------------------------------------
// Attention v4: 256 thr / 4 waves; K/V tile (32 keys) staged in LDS, shared
// by all 4 waves; each wave owns 64 q-rows (g=4 groups of 16). Double-
// buffered staging, ONE barrier per tile (prefetch to regs at loop top,
// ds_write to the other buffer after compute). P transpose via per-wave
// ping-pong LDS scratch, paired-column packed b32 (conflict-free; verified
// bank arithmetic: all patterns <=2-way). p = exp2(s) (log2e folded into Q);
// row-sums via ones-MFMA. V tok-permuted by projection to match pair order.
// Grid (SEQ/256, B*H). Y out: bf16 (B,L,C).
// ---------------------------------------------------------------------------
__global__ __launch_bounds__(256) void attn_v4_kernel(
    const __bf16* __restrict__ Qh, const __bf16* __restrict__ Kh,
    const __bf16* __restrict__ Vht, __bf16* __restrict__ Y)
{
    __shared__ __align__(16) __bf16 Ks[2][32][72];       // [buf][key][dim]
    __shared__ __align__(16) __bf16 Vt[2][64][48];       // [buf][dim][key]
    __shared__ __align__(16) unsigned int Pf[4][2][16][36]; // [wave][g&1][q][pair]

    const int tid  = threadIdx.x;
    const int w    = tid >> 6;
    const int lane = tid & 63;
    const int quad = lane >> 4;
    const int c    = lane & 15;
    const int bh   = blockIdx.y;
    const int b    = bh >> 4;
    const int h    = bh & 15;
    const int qbase = blockIdx.x * 256 + w * 64;

    const __bf16* Qg = Qh + (size_t)bh * SEQ * HDIM;
    const __bf16* Kg = Kh + (size_t)bh * SEQ * HDIM;
    const __bf16* Vg = Vht + (size_t)(h * HDIM) * TOKS + (size_t)b * SEQ;

    bf16x8 qf[4][2];
#pragma unroll
    for (int g = 0; g < 4; g++) {
        qf[g][0] = *(const bf16x8*)&Qg[(size_t)(qbase + g * 16 + c) * HDIM + quad * 8];
        qf[g][1] = *(const bf16x8*)&Qg[(size_t)(qbase + g * 16 + c) * HDIM + 32 + quad * 8];
    }

    bf16x8 ones;
#pragma unroll
    for (int j = 0; j < 8; j++) ones[j] = (__bf16)1.0f;

    f32x4 O[4][4];
    f32x4 L[4];
#pragma unroll
    for (int g = 0; g < 4; g++) {
        L[g] = (f32x4){0, 0, 0, 0};
#pragma unroll
        for (int i = 0; i < 4; i++) O[g][i] = (f32x4){0, 0, 0, 0};
    }

    // cooperative staging indices (256 threads)
    const int krow = tid >> 3, kcol = (tid & 7) * 8;   // K: 32 rows x 64 dims
    const int vrow = tid >> 2, vcol = (tid & 3) * 8;   // V: 64 dims x 32 keys

    // preload tile 0
    {
        const bf16x8 k0 = *(const bf16x8*)&Kg[(size_t)krow * HDIM + kcol];
        const bf16x8 v0 = *(const bf16x8*)&Vg[(size_t)vrow * TOKS + vcol];
        *(bf16x8*)&Ks[0][krow][kcol] = k0;
        *(bf16x8*)&Vt[0][vrow][vcol] = v0;
    }
    __syncthreads();

    int buf = 0;
    for (int t0 = 0; t0 < SEQ; t0 += 32) {
        const int tn = t0 + 32;
        bf16x8 kpre, vpre;
        if (tn < SEQ) {
            kpre = *(const bf16x8*)&Kg[(size_t)(tn + krow) * HDIM + kcol];
            vpre = *(const bf16x8*)&Vg[(size_t)vrow * TOKS + tn + vcol];
        }

        const bf16x8 k00 = *(const bf16x8*)&Ks[buf][c][quad * 8];
        const bf16x8 k01 = *(const bf16x8*)&Ks[buf][c][32 + quad * 8];
        const bf16x8 k10 = *(const bf16x8*)&Ks[buf][16 + c][quad * 8];
        const bf16x8 k11 = *(const bf16x8*)&Ks[buf][16 + c][32 + quad * 8];
        const bf16x8 v0 = *(const bf16x8*)&Vt[buf][c][quad * 8];
        const bf16x8 v1 = *(const bf16x8*)&Vt[buf][16 + c][quad * 8];
        const bf16x8 v2 = *(const bf16x8*)&Vt[buf][32 + c][quad * 8];
        const bf16x8 v3 = *(const bf16x8*)&Vt[buf][48 + c][quad * 8];

#pragma unroll
        for (int g = 0; g < 4; g++) {
            const int pg = g & 1;
            f32x4 s0 = {0, 0, 0, 0}, s1 = {0, 0, 0, 0};
            s0 = MFMA16(qf[g][0], k00, s0);
            s0 = MFMA16(qf[g][1], k01, s0);
            s1 = MFMA16(qf[g][0], k10, s1);
            s1 = MFMA16(qf[g][1], k11, s1);
#pragma unroll
            for (int r = 0; r < 4; r++) {
                union { bf16x2 v; unsigned int u; } pk;
                pk.v[0] = (__bf16)__builtin_amdgcn_exp2f(s0[r]);
                pk.v[1] = (__bf16)__builtin_amdgcn_exp2f(s1[r]);
                Pf[w][pg][quad * 4 + r][c] = pk.u;
            }
            const bf16x8 pf = *(const bf16x8*)&Pf[w][pg][c][quad * 4];
            L[g]    = MFMA16(pf, ones, L[g]);
            O[g][0] = MFMA16(pf, v0, O[g][0]);
            O[g][1] = MFMA16(pf, v1, O[g][1]);
            O[g][2] = MFMA16(pf, v2, O[g][2]);
            O[g][3] = MFMA16(pf, v3, O[g][3]);
        }

        if (tn < SEQ) {
            *(bf16x8*)&Ks[buf ^ 1][krow][kcol] = kpre;
            *(bf16x8*)&Vt[buf ^ 1][vrow][vcol] = vpre;
        }
        __syncthreads();
        buf ^= 1;
    }

    __bf16* Yb = Y + (size_t)b * SEQ * CDIM;
#pragma unroll
    for (int g = 0; g < 4; g++) {
#pragma unroll
        for (int r = 0; r < 4; r++) {
            const float inv = 1.0f / L[g][r];
            const int l = qbase + g * 16 + quad * 4 + r;
            __bf16* yp = Yb + (size_t)l * CDIM + h * HDIM + c;
            yp[0]  = (__bf16)(O[g][0][r] * inv);
            yp[16] = (__bf16)(O[g][1][r] * inv);
            yp[32] = (__bf16)(O[g][2][r] * inv);
            yp[48] = (__bf16)(O[g][3][r] * inv);
        }
    }
}

// ---------------------------------------------------------------------------

extern "C" void kernel_launch(void* const* d_in, const int* in_sizes, int n_in,
                              void* d_out, int out_size, void* d_ws, size_t ws_size,
                              hipStream_t stream)
{
    const float* q  = (const float*)d_in[0];
    const float* k  = (const float*)d_in[1];
    const float* v  = (const float*)d_in[2];
    const float* Wq = (const float*)d_in[3];
    const float* bq = (const float*)d_in[4];
    const float* Wk = (const float*)d_in[5];
    const float* bk = (const float*)d_in[6];
    const float* Wv = (const float*)d_in[7];
    const float* bv = (const float*)d_in[8];
    const float* Wo = (const float*)d_in[9];
    const float* bo = (const float*)d_in[10];
    float* out = (float*)d_out;

    const size_t MAT = (size_t)TOKS * CDIM;
    const size_t WN  = (size_t)CDIM * CDIM;

    __bf16* p   = (__bf16*)d_ws;
    __bf16* qb  = p; p += MAT;
    __bf16* kb  = p; p += MAT;
    __bf16* vb  = p; p += MAT;
    __bf16* Wqt = p; p += WN;
    __bf16* Wkt = p; p += WN;
    __bf16* Wvt = p; p += WN;
    __bf16* Wot = p; p += WN;
    __bf16* Qh  = p; p += MAT;   // (B,H,L,D), scaled by QSCALE
    __bf16* Kh  = p; p += MAT;   // (B,H,L,D)
    __bf16* Vht = p; p += MAT;   // [chan][tok'], pair-permuted toks
    __bf16* Yb  = qb;            // alias: qb dead after QKV GEMM

    prep_kernel<<<dim3(7168), dim3(256), 0, stream>>>(
        q, k, v, qb, kb, vb, Wq, Wk, Wv, Wo, Wqt, Wkt, Wvt, Wot);

    qkv_gemm_kernel<<<dim3(8, 32, 3), dim3(256), 0, stream>>>(
        qb, kb, vb, Wqt, Wkt, Wvt, bq, bk, bv, Qh, Kh, Vht);

    attn_v4_kernel<<<dim3(SEQ / 256, BATCH * NHEAD), dim3(256), 0, stream>>>(Qh, Kh, Vht, Yb);

    out_gemm_kernel<<<dim3(16, 32), dim3(256), 0, stream>>>(Yb, Wot, bo, out);
}

// Round 7
// 234.247 us; speedup vs baseline: 1.1215x; 1.0285x over previous
//
#include <hip/hip_runtime.h>
#include <math.h>

#define BATCH 2
#define SEQ   2048
#define CDIM  1024
#define NHEAD 16
#define HDIM  64
#define TOKS  (BATCH * SEQ)   // 4096

typedef __bf16 bf16x8 __attribute__((ext_vector_type(8)));
typedef __bf16 bf16x2 __attribute__((ext_vector_type(2)));
typedef float  f32x4  __attribute__((ext_vector_type(4)));

#define MFMA16(a, b, c) __builtin_amdgcn_mfma_f32_16x16x32_bf16(a, b, c, 0, 0, 0)

// 0.125 * log2(e): folded into Q projection so p = exp2(s) == softmax-exact
#define QSCALE 0.1803368801111204f

__device__ __forceinline__ void gload_lds16(const __bf16* g, __bf16* l) {
    __builtin_amdgcn_global_load_lds(
        (const __attribute__((address_space(1))) unsigned int*)g,
        (__attribute__((address_space(3))) unsigned int*)l, 16, 0, 0);
}

// ---------------------------------------------------------------------------
// Prep: blocks [0,6144): fp32->bf16 convert of q,k,v (2048 blocks each).
//       blocks [6144,7168): W (KxN fp32) -> Wt (NxK bf16) transpose, 4 mats.
// ---------------------------------------------------------------------------
__global__ __launch_bounds__(256) void prep_kernel(
    const float* __restrict__ q, const float* __restrict__ k, const float* __restrict__ v,
    __bf16* __restrict__ qo, __bf16* __restrict__ ko, __bf16* __restrict__ vo,
    const float* __restrict__ W0, const float* __restrict__ W1,
    const float* __restrict__ W2, const float* __restrict__ W3,
    __bf16* __restrict__ T0, __bf16* __restrict__ T1,
    __bf16* __restrict__ T2, __bf16* __restrict__ T3)
{
    __shared__ __bf16 Ts[64][72];
    const int bx = blockIdx.x;
    const int tid = threadIdx.x;

    if (bx < 6144) {
        const int t = bx >> 11;
        const size_t i = ((size_t)(bx & 2047) * 256 + tid) * 8;
        const float* s = t == 0 ? q : (t == 1 ? k : v);
        __bf16* d = t == 0 ? qo : (t == 1 ? ko : vo);
        const float4 x = *(const float4*)&s[i];
        const float4 y = *(const float4*)&s[i + 4];
        bf16x8 o;
        o[0] = (__bf16)x.x; o[1] = (__bf16)x.y; o[2] = (__bf16)x.z; o[3] = (__bf16)x.w;
        o[4] = (__bf16)y.x; o[5] = (__bf16)y.y; o[6] = (__bf16)y.z; o[7] = (__bf16)y.w;
        *(bf16x8*)&d[i] = o;
        return;
    }

    const int t  = bx - 6144;
    const int z  = t >> 8;
    const int ry = (t & 255) >> 4;
    const int rx = t & 15;
    const float* W = z == 0 ? W0 : z == 1 ? W1 : z == 2 ? W2 : W3;
    __bf16* T = z == 0 ? T0 : z == 1 ? T1 : z == 2 ? T2 : T3;
    const int rb = ry * 64, cb = rx * 64;
    const int r = tid >> 4;
    const int c4 = (tid & 15) * 4;
#pragma unroll
    for (int p = 0; p < 4; p++) {
        const int rr = p * 16 + r;
        const float4 w4 = *(const float4*)&W[(size_t)(rb + rr) * CDIM + cb + c4];
        Ts[c4 + 0][rr] = (__bf16)w4.x;
        Ts[c4 + 1][rr] = (__bf16)w4.y;
        Ts[c4 + 2][rr] = (__bf16)w4.z;
        Ts[c4 + 3][rr] = (__bf16)w4.w;
    }
    __syncthreads();
    const int n = tid >> 2;
    const int k16 = (tid & 3) * 16;
    *(bf16x8*)&T[(size_t)(cb + n) * CDIM + rb + k16]     = *(const bf16x8*)&Ts[n][k16];
    *(bf16x8*)&T[(size_t)(cb + n) * CDIM + rb + k16 + 8] = *(const bf16x8*)&Ts[n][k16 + 8];
}

// ---------------------------------------------------------------------------
// Fused QKV projection GEMM (m97 structure), one dispatch, z selects:
//   z=0: Qh = (q@Wq + bq)*QSCALE  -> (B,H,L,D) bf16
//   z=1: Kh = (k@Wk + bk)         -> (B,H,L,D) bf16
//   z=2: Vht = (Wv^T @ v^T + bv)  -> [chan][tok'] bf16, tok' key-pair-permuted
//        within each 32-group: pos(n) = 2*(n&15) + (n>>4)  (for attn P pairing)
// ---------------------------------------------------------------------------
__global__ __launch_bounds__(256) void qkv_gemm_kernel(
    const __bf16* __restrict__ qb, const __bf16* __restrict__ kb,
    const __bf16* __restrict__ vb,
    const __bf16* __restrict__ Wqt, const __bf16* __restrict__ Wkt,
    const __bf16* __restrict__ Wvt,
    const float* __restrict__ bq, const float* __restrict__ bk,
    const float* __restrict__ bv,
    __bf16* __restrict__ Qh, __bf16* __restrict__ Kh, __bf16* __restrict__ Vht)
{
    __shared__ __bf16 As[128 * 32];
    __shared__ __bf16 Bs[128 * 32];

    const int z = blockIdx.z;
    const __bf16* A    = z == 0 ? qb : z == 1 ? kb : Wvt;
    const __bf16* Bt   = z == 0 ? Wqt : z == 1 ? Wkt : vb;
    const float*  bias = z == 0 ? bq : z == 1 ? bk : bv;

    const int tid  = threadIdx.x;
    const int w    = tid >> 6;
    const int lane = tid & 63;
    const int quad = lane >> 4;
    const int c    = lane & 15;
    const int wm   = w >> 1;
    const int wn   = w & 1;
    const int rowBase = (z == 2 ? blockIdx.x : blockIdx.y) * 128;
    const int colBase = (z == 2 ? blockIdx.y : blockIdx.x) * 128;

    const int sr = lane >> 2;
    const int sk = (lane & 3) * 8;

    f32x4 acc[4][4];
#pragma unroll
    for (int i = 0; i < 4; i++)
#pragma unroll
        for (int j = 0; j < 4; j++) acc[i][j] = (f32x4){0, 0, 0, 0};

    for (int k0 = 0; k0 < CDIM; k0 += 32) {
#pragma unroll
        for (int j = 0; j < 2; j++) {
            const int r0 = (w * 2 + j) * 16;
            gload_lds16(A  + (size_t)(rowBase + r0 + sr) * CDIM + k0 + sk, &As[r0 * 32]);
            gload_lds16(Bt + (size_t)(colBase + r0 + sr) * CDIM + k0 + sk, &Bs[r0 * 32]);
        }
        __syncthreads();

        bf16x8 af[4], bf[4];
#pragma unroll
        for (int i = 0; i < 4; i++) {
            af[i] = *(const bf16x8*)&As[(wm * 64 + i * 16 + c) * 32 + quad * 8];
            bf[i] = *(const bf16x8*)&Bs[(wn * 64 + i * 16 + c) * 32 + quad * 8];
        }
#pragma unroll
        for (int mi = 0; mi < 4; mi++)
#pragma unroll
            for (int ni = 0; ni < 4; ni++)
                acc[mi][ni] = MFMA16(af[mi], bf[ni], acc[mi][ni]);
        __syncthreads();
    }

#pragma unroll
    for (int mi = 0; mi < 4; mi++) {
#pragma unroll
        for (int ni = 0; ni < 4; ni++) {
            const int col = colBase + wn * 64 + ni * 16 + c;
#pragma unroll
            for (int r = 0; r < 4; r++) {
                const int row = rowBase + wm * 64 + mi * 16 + quad * 4 + r;
                const float val = acc[mi][ni][r];
                if (z == 2) {
                    // permuted-tok V write: pos within 32-group = 2*(n&15)+(n>>4)
                    const int col2 = (col & ~31) | (((col & 15) << 1) | ((col >> 4) & 1));
                    Vht[(size_t)row * TOKS + col2] = (__bf16)(val + bias[row]);
                } else {
                    const int b = row >> 11, l = row & 2047;
                    const int h = col >> 6,  d = col & 63;
                    const float s = (z == 0) ? QSCALE : 1.0f;
                    __bf16* outp = (z == 0) ? Qh : Kh;
                    outp[((((size_t)b * NHEAD + h) * SEQ) + l) * HDIM + d] =
                        (__bf16)((val + bias[col]) * s);
                }
            }
        }
    }
}

// ---------------------------------------------------------------------------
// Final projection GEMM: out(fp32) = Yb(bf16) @ Wot^T + bo.
// 128x64 tile -> grid (16,32) = 512 blocks (2 blocks/CU for overlap).
// ---------------------------------------------------------------------------
__global__ __launch_bounds__(256) void out_gemm_kernel(
    const __bf16* __restrict__ A, const __bf16* __restrict__ Bt,
    const float* __restrict__ bias, float* __restrict__ out)
{
    __shared__ __bf16 As[128 * 32];
    __shared__ __bf16 Bs[64 * 32];

    const int tid  = threadIdx.x;
    const int w    = tid >> 6;
    const int lane = tid & 63;
    const int quad = lane >> 4;
    const int c    = lane & 15;
    const int wm   = w >> 1;
    const int wn   = w & 1;
    const int rowBase = blockIdx.y * 128;
    const int colBase = blockIdx.x * 64;
    const int sr = lane >> 2;
    const int sk = (lane & 3) * 8;

    f32x4 acc[4][2];
#pragma unroll
    for (int i = 0; i < 4; i++)
#pragma unroll
        for (int j = 0; j < 2; j++) acc[i][j] = (f32x4){0, 0, 0, 0};

    for (int k0 = 0; k0 < CDIM; k0 += 32) {
#pragma unroll
        for (int j = 0; j < 2; j++) {
            const int r0 = (w * 2 + j) * 16;
            gload_lds16(A + (size_t)(rowBase + r0 + sr) * CDIM + k0 + sk, &As[r0 * 32]);
        }
        gload_lds16(Bt + (size_t)(colBase + w * 16 + sr) * CDIM + k0 + sk, &Bs[w * 16 * 32]);
        __syncthreads();

        bf16x8 af[4], bf[2];
#pragma unroll
        for (int i = 0; i < 4; i++)
            af[i] = *(const bf16x8*)&As[(wm * 64 + i * 16 + c) * 32 + quad * 8];
#pragma unroll
        for (int i = 0; i < 2; i++)
            bf[i] = *(const bf16x8*)&Bs[(wn * 32 + i * 16 + c) * 32 + quad * 8];
#pragma unroll
        for (int mi = 0; mi < 4; mi++)
#pragma unroll
            for (int ni = 0; ni < 2; ni++)
                acc[mi][ni] = MFMA16(af[mi], bf[ni], acc[mi][ni]);
        __syncthreads();
    }

#pragma unroll
    for (int mi = 0; mi < 4; mi++) {
#pragma unroll
        for (int ni = 0; ni < 2; ni++) {
            const int col = colBase + wn * 32 + ni * 16 + c;
#pragma unroll
            for (int r = 0; r < 4; r++) {
                const int row = rowBase + wm * 64 + mi * 16 + quad * 4 + r;
                out[(size_t)row * CDIM + col] = acc[mi][ni][r] + bias[col];
            }
        }
    }
}

// ---------------------------------------------------------------------------
// Attention v5: 256 thr / 4 waves; each wave owns 32 q-rows (g=2); block
// covers 128 q-rows -> grid (B*H, SEQ/128) = 512 blocks = 2 blocks/CU
// (2 waves/SIMD so MFMA of one wave hides VALU/LDS latency of the other).
// XCD-aware mapping: x = head (fastest) so block id % 8 == bh % 8 — all 16
// q-tile blocks of a head pin to one XCD; per-XCD K/V working set 2 MB < L2.
// K/V tile (32 keys) LDS-staged, double-buffered, one barrier per tile.
// P transpose: per-wave ping-pong LDS, paired-column packed b32 (bank-free).
// p = exp2(s) (log2e folded into Q); row-sums via ones-MFMA; V tok-permuted
// by the projection to match the pair order. Y out: bf16 (B,L,C).
// ---------------------------------------------------------------------------
__global__ __launch_bounds__(256) void attn_v5_kernel(
    const __bf16* __restrict__ Qh, const __bf16* __restrict__ Kh,
    const __bf16* __restrict__ Vht, __bf16* __restrict__ Y)
{
    __shared__ __align__(16) __bf16 Ks[2][32][72];          // [buf][key][dim]
    __shared__ __align__(16) __bf16 Vt[2][64][48];          // [buf][dim][key]
    __shared__ __align__(16) unsigned int Pf[4][2][16][36]; // [wave][g][q][pair]

    const int tid  = threadIdx.x;
    const int w    = tid >> 6;
    const int lane = tid & 63;
    const int quad = lane >> 4;
    const int c    = lane & 15;
    const int bh   = blockIdx.x;             // head index FASTEST -> XCD pin
    const int b    = bh >> 4;
    const int h    = bh & 15;
    const int qbase = blockIdx.y * 128 + w * 32;

    const __bf16* Qg = Qh + (size_t)bh * SEQ * HDIM;
    const __bf16* Kg = Kh + (size_t)bh * SEQ * HDIM;
    const __bf16* Vg = Vht + (size_t)(h * HDIM) * TOKS + (size_t)b * SEQ;

    bf16x8 qf[2][2];
#pragma unroll
    for (int g = 0; g < 2; g++) {
        qf[g][0] = *(const bf16x8*)&Qg[(size_t)(qbase + g * 16 + c) * HDIM + quad * 8];
        qf[g][1] = *(const bf16x8*)&Qg[(size_t)(qbase + g * 16 + c) * HDIM + 32 + quad * 8];
    }

    bf16x8 ones;
#pragma unroll
    for (int j = 0; j < 8; j++) ones[j] = (__bf16)1.0f;

    f32x4 O[2][4];
    f32x4 L[2];
#pragma unroll
    for (int g = 0; g < 2; g++) {
        L[g] = (f32x4){0, 0, 0, 0};
#pragma unroll
        for (int i = 0; i < 4; i++) O[g][i] = (f32x4){0, 0, 0, 0};
    }

    // cooperative staging indices (256 threads)
    const int krow = tid >> 3, kcol = (tid & 7) * 8;   // K: 32 rows x 64 dims
    const int vrow = tid >> 2, vcol = (tid & 3) * 8;   // V: 64 dims x 32 keys

    // preload tile 0
    {
        const bf16x8 k0 = *(const bf16x8*)&Kg[(size_t)krow * HDIM + kcol];
        const bf16x8 v0 = *(const bf16x8*)&Vg[(size_t)vrow * TOKS + vcol];
        *(bf16x8*)&Ks[0][krow][kcol] = k0;
        *(bf16x8*)&Vt[0][vrow][vcol] = v0;
    }
    __syncthreads();

    int buf = 0;
    for (int t0 = 0; t0 < SEQ; t0 += 32) {
        const int tn = t0 + 32;
        bf16x8 kpre, vpre;
        if (tn < SEQ) {
            kpre = *(const bf16x8*)&Kg[(size_t)(tn + krow) * HDIM + kcol];
            vpre = *(const bf16x8*)&Vg[(size_t)vrow * TOKS + tn + vcol];
        }

        const bf16x8 k00 = *(const bf16x8*)&Ks[buf][c][quad * 8];
        const bf16x8 k01 = *(const bf16x8*)&Ks[buf][c][32 + quad * 8];
        const bf16x8 k10 = *(const bf16x8*)&Ks[buf][16 + c][quad * 8];
        const bf16x8 k11 = *(const bf16x8*)&Ks[buf][16 + c][32 + quad * 8];
        const bf16x8 v0 = *(const bf16x8*)&Vt[buf][c][quad * 8];
        const bf16x8 v1 = *(const bf16x8*)&Vt[buf][16 + c][quad * 8];
        const bf16x8 v2 = *(const bf16x8*)&Vt[buf][32 + c][quad * 8];
        const bf16x8 v3 = *(const bf16x8*)&Vt[buf][48 + c][quad * 8];

#pragma unroll
        for (int g = 0; g < 2; g++) {
            f32x4 s0 = {0, 0, 0, 0}, s1 = {0, 0, 0, 0};
            s0 = MFMA16(qf[g][0], k00, s0);
            s0 = MFMA16(qf[g][1], k01, s0);
            s1 = MFMA16(qf[g][0], k10, s1);
            s1 = MFMA16(qf[g][1], k11, s1);
#pragma unroll
            for (int r = 0; r < 4; r++) {
                union { bf16x2 v; unsigned int u; } pk;
                pk.v[0] = (__bf16)__builtin_amdgcn_exp2f(s0[r]);
                pk.v[1] = (__bf16)__builtin_amdgcn_exp2f(s1[r]);
                Pf[w][g][quad * 4 + r][c] = pk.u;
            }
            const bf16x8 pf = *(const bf16x8*)&Pf[w][g][c][quad * 4];
            L[g]    = MFMA16(pf, ones, L[g]);
            O[g][0] = MFMA16(pf, v0, O[g][0]);
            O[g][1] = MFMA16(pf, v1, O[g][1]);
            O[g][2] = MFMA16(pf, v2, O[g][2]);
            O[g][3] = MFMA16(pf, v3, O[g][3]);
        }

        if (tn < SEQ) {
            *(bf16x8*)&Ks[buf ^ 1][krow][kcol] = kpre;
            *(bf16x8*)&Vt[buf ^ 1][vrow][vcol] = vpre;
        }
        __syncthreads();
        buf ^= 1;
    }

    __bf16* Yb = Y + (size_t)b * SEQ * CDIM;
#pragma unroll
    for (int g = 0; g < 2; g++) {
#pragma unroll
        for (int r = 0; r < 4; r++) {
            const float inv = 1.0f / L[g][r];
            const int l = qbase + g * 16 + quad * 4 + r;
            __bf16* yp = Yb + (size_t)l * CDIM + h * HDIM + c;
            yp[0]  = (__bf16)(O[g][0][r] * inv);
            yp[16] = (__bf16)(O[g][1][r] * inv);
            yp[32] = (__bf16)(O[g][2][r] * inv);
            yp[48] = (__bf16)(O[g][3][r] * inv);
        }
    }
}

// ---------------------------------------------------------------------------

extern "C" void kernel_launch(void* const* d_in, const int* in_sizes, int n_in,
                              void* d_out, int out_size, void* d_ws, size_t ws_size,
                              hipStream_t stream)
{
    const float* q  = (const float*)d_in[0];
    const float* k  = (const float*)d_in[1];
    const float* v  = (const float*)d_in[2];
    const float* Wq = (const float*)d_in[3];
    const float* bq = (const float*)d_in[4];
    const float* Wk = (const float*)d_in[5];
    const float* bk = (const float*)d_in[6];
    const float* Wv = (const float*)d_in[7];
    const float* bv = (const float*)d_in[8];
    const float* Wo = (const float*)d_in[9];
    const float* bo = (const float*)d_in[10];
    float* out = (float*)d_out;

    const size_t MAT = (size_t)TOKS * CDIM;
    const size_t WN  = (size_t)CDIM * CDIM;

    __bf16* p   = (__bf16*)d_ws;
    __bf16* qb  = p; p += MAT;
    __bf16* kb  = p; p += MAT;
    __bf16* vb  = p; p += MAT;
    __bf16* Wqt = p; p += WN;
    __bf16* Wkt = p; p += WN;
    __bf16* Wvt = p; p += WN;
    __bf16* Wot = p; p += WN;
    __bf16* Qh  = p; p += MAT;   // (B,H,L,D), scaled by QSCALE
    __bf16* Kh  = p; p += MAT;   // (B,H,L,D)
    __bf16* Vht = p; p += MAT;   // [chan][tok'], pair-permuted toks
    __bf16* Yb  = qb;            // alias: qb dead after QKV GEMM

    prep_kernel<<<dim3(7168), dim3(256), 0, stream>>>(
        q, k, v, qb, kb, vb, Wq, Wk, Wv, Wo, Wqt, Wkt, Wvt, Wot);

    qkv_gemm_kernel<<<dim3(8, 32, 3), dim3(256), 0, stream>>>(
        qb, kb, vb, Wqt, Wkt, Wvt, bq, bk, bv, Qh, Kh, Vht);

    attn_v5_kernel<<<dim3(BATCH * NHEAD, SEQ / 128), dim3(256), 0, stream>>>(Qh, Kh, Vht, Yb);

    out_gemm_kernel<<<dim3(16, 32), dim3(256), 0, stream>>>(Yb, Wot, bo, out);
}